// Round 5
// baseline (1143.537 us; speedup 1.0000x reference)
//
#include <hip/hip_runtime.h>
#include <math.h>

#define B_ 4
#define S_ 2048
#define D_ 1024
#define F_ 4096
#define E_ 8
#define T_ 8192
#define LBW_ 0.01f
#define HROWS_ 17408  // sum of per-expert 128-padded counts <= 16384 + 8*127 = 17400

#define BUFB 49152    // bytes per LDS buffer: A-tile 256x64x2 (32768) + B-tile 128x64x2 (16384)
#define ABYTES 32768

typedef unsigned short u16;
typedef __attribute__((ext_vector_type(8))) short bf16x8;
typedef __attribute__((ext_vector_type(4))) float f32x4;

// async global->LDS, 16B per lane; LDS dest = wave-uniform base + lane*16
#define GLOAD16(gp, lp) __builtin_amdgcn_global_load_lds( \
    (const __attribute__((address_space(1))) void*)(gp),  \
    (__attribute__((address_space(3))) void*)(lp), 16, 0, 0)

__device__ __forceinline__ u16 f2b(float f) {
    unsigned u = __float_as_uint(f);
    u = (u + 0x7FFFu + ((u >> 16) & 1u)) >> 16;   // RNE f32 -> bf16
    return (u16)u;
}
__device__ __forceinline__ float gelu_f(float v) {
    return 0.5f * v * (1.0f + erff(v * 0.70710678118654752440f));
}

// ------- per-expert transpose + convert: src (R x C f32, row-major) -> dst (C x R bf16) -------
__global__ __launch_bounds__(256) void cvt_T_kernel(const float* __restrict__ src,
                                                    u16* __restrict__ dst, int R, int C) {
    __shared__ u16 t[64][72];
    const int e = blockIdx.z;
    const float* s = src + (size_t)e * R * C;
    u16* d = dst + (size_t)e * R * C;
    const int r0 = blockIdx.y * 64, c0 = blockIdx.x * 64;
    const int tid = threadIdx.x;
    {
        int rr = tid >> 2, cq = (tid & 3) * 16;
        #pragma unroll
        for (int j = 0; j < 16; j += 4) {
            float4 v = *(const float4*)(s + (size_t)(r0 + rr) * C + c0 + cq + j);
            t[cq + j + 0][rr] = f2b(v.x);
            t[cq + j + 1][rr] = f2b(v.y);
            t[cq + j + 2][rr] = f2b(v.z);
            t[cq + j + 3][rr] = f2b(v.w);
        }
    }
    __syncthreads();
    {
        int cr = tid >> 2, rq = (tid & 3) * 16;
        #pragma unroll
        for (int j = 0; j < 16; j += 8) {
            int4 pk; u16* pw = (u16*)&pk;
            #pragma unroll
            for (int jj = 0; jj < 8; ++jj) pw[jj] = t[cr][rq + j + jj];
            *(int4*)(d + (size_t)(c0 + cr) * R + r0 + rq + j) = pk;
        }
    }
}

// ------- gate: logits (f64), softmax, top-2, routing lists, loss partials; also x->bf16 -------
__global__ __launch_bounds__(64) void gate_kernel(
    const float* __restrict__ x, const float* __restrict__ ew,
    const float* __restrict__ gw, const float* __restrict__ gb,
    u16* __restrict__ xb,
    float* __restrict__ combine, int* __restrict__ idx, int* __restrict__ cnt,
    int* __restrict__ fcnt, float* __restrict__ psum)
{
    const int t = blockIdx.x, l = threadIdx.x;
    const float* xr = x + (size_t)t * D_;
    double acc[E_];
    #pragma unroll
    for (int e = 0; e < E_; ++e) acc[e] = 0.0;
    u16 xw[16];
    #pragma unroll
    for (int kk = 0; kk < 16; kk += 4) {
        float4 xv = *(const float4*)(xr + l * 16 + kk);
        float xs[4] = {xv.x, xv.y, xv.z, xv.w};
        #pragma unroll
        for (int j = 0; j < 4; ++j) {
            xw[kk + j] = f2b(xs[j]);
            const float* gr = gw + (size_t)(l * 16 + kk + j) * E_;
            float4 g0 = *(const float4*)(gr);
            float4 g1 = *(const float4*)(gr + 4);
            acc[0] += (double)xs[j] * g0.x;  acc[1] += (double)xs[j] * g0.y;
            acc[2] += (double)xs[j] * g0.z;  acc[3] += (double)xs[j] * g0.w;
            acc[4] += (double)xs[j] * g1.x;  acc[5] += (double)xs[j] * g1.y;
            acc[6] += (double)xs[j] * g1.z;  acc[7] += (double)xs[j] * g1.w;
        }
    }
    *(int4*)(xb + (size_t)t * D_ + l * 16)     = *(int4*)(xw);
    *(int4*)(xb + (size_t)t * D_ + l * 16 + 8) = *(int4*)(xw + 8);
    #pragma unroll
    for (int e = 0; e < E_; ++e) {
        #pragma unroll
        for (int m = 32; m > 0; m >>= 1) acc[e] += __shfl_xor(acc[e], m);
    }
    if (l == 0) {
        const int b = t / S_;
        double p[E_]; double mx = -1e300;
        #pragma unroll
        for (int e = 0; e < E_; ++e) {
            p[e] = acc[e] + (double)gb[e] + (double)ew[b * E_ + e];
            mx = fmax(mx, p[e]);
        }
        double s = 0.0;
        #pragma unroll
        for (int e = 0; e < E_; ++e) { p[e] = exp(p[e] - mx); s += p[e]; }
        double inv = 1.0 / s;
        #pragma unroll
        for (int e = 0; e < E_; ++e) p[e] *= inv;
        double m1 = -1.0; int e1 = 0;
        #pragma unroll
        for (int e = 0; e < E_; ++e) if (p[e] > m1) { m1 = p[e]; e1 = e; }
        double m2 = -1.0; int e2 = 0;
        #pragma unroll
        for (int e = 0; e < E_; ++e) if (e != e1 && p[e] > m2) { m2 = p[e]; e2 = e; }
        float c1 = (float)(m1 / (m1 + m2)), c2 = (float)(m2 / (m1 + m2));
        #pragma unroll
        for (int e = 0; e < E_; ++e)
            combine[t * E_ + e] = (e == e1) ? c1 : ((e == e2) ? c2 : 0.0f);
        int q1 = atomicAdd(&cnt[e1], 1); idx[e1 * T_ + q1] = t;
        int q2 = atomicAdd(&cnt[e2], 1); idx[e2 * T_ + q2] = t;
        atomicAdd(&fcnt[(t & 63) * E_ + e1], 1);
        #pragma unroll
        for (int e = 0; e < E_; ++e) atomicAdd(&psum[(t & 63) * E_ + e], (float)p[e]);
    }
}

__global__ void offsets_kernel(const int* __restrict__ cnt, int* __restrict__ off) {
    if (threadIdx.x == 0 && blockIdx.x == 0) {
        int o = 0;
        for (int e = 0; e < E_; ++e) { off[e] = o; o += ((cnt[e] + 127) >> 7) << 7; }
    }
}

// ---- fused-expert GEMM, 256x128 tile, BK=64, 3-buffer counted-vmcnt + expert->XCD 1D grid ----
// gid = e + 8*tm + 256*tn : e->XCD (8 XCDs), tm fast within XCD so consecutive same-XCD
// blocks share (e, tn) => B-strip (128 cols x K x 2B ~ 0.5-1 MB) stays L2-resident; A-panel
// re-reads across tn are absorbed by L3 (h=134MB, w=67MB per expert-set all fit in 256MB).
// IS_G1: A = xb gathered rows (K=1024), out = h (gelu+b1).  !IS_G1: A = h rows (K=4096), out += atomic.
template<int NT, bool IS_G1>
__global__ __launch_bounds__(512, 2) void moe_gemm_kernel(
    const u16* __restrict__ Aglob, const u16* __restrict__ Wt,
    const float* __restrict__ bias, const float* __restrict__ combine,
    const int* __restrict__ idxAll, const int* __restrict__ cntAll,
    const int* __restrict__ off,
    u16* __restrict__ hOut, float* __restrict__ out)
{
    constexpr int KD = NT * 64;
    const int gid = blockIdx.x;
    const int e = gid & 7;
    const int tm = (gid >> 3) & 31;
    const int tn = gid >> 8;
    const int cnt = cntAll[e];
    if (tm * 256 >= cnt) return;
    const int base = off[e];
    const int* idx_e = idxAll + e * T_;
    const u16* Bsrc = Wt + (size_t)e * ((size_t)D_ * F_);

    __shared__ __align__(16) char ldsr[3 * BUFB];

    const int tid = threadIdx.x;
    const int l = tid & 63, wid = tid >> 6;
    const int wm = (wid >> 1) * 64, wn = (wid & 1) * 64;   // wave tile 64x64 within 256x128
    const int lr = l & 15, lg = l >> 4;

    // ---- stage source pointers (swizzled chunk: LDS chunk q of row r holds global chunk q^(r&7)) ----
    const int lrow8 = l >> 3;                 // row within 8-row slab = (r & 7)
    const int schunk = (l & 7) ^ lrow8;       // source chunk for this lane
    const u16* aptr[4]; const u16* bptr[2];
    #pragma unroll
    for (int i = 0; i < 4; ++i) {
        int row = (i * 8 + wid) * 8 + lrow8;            // 0..255
        int r = tm * 256 + row;
        if (IS_G1) {
            int tok = (r < cnt) ? idx_e[r] : idx_e[0];
            aptr[i] = Aglob + (size_t)tok * KD + schunk * 8;
        } else {
            int hr = base + r; if (hr > HROWS_ - 1) hr = HROWS_ - 1;   // clamp straddle reads
            aptr[i] = Aglob + (size_t)hr * KD + schunk * 8;
        }
    }
    #pragma unroll
    for (int j = 0; j < 2; ++j) {
        int row = (j * 8 + wid) * 8 + lrow8;            // 0..127
        bptr[j] = Bsrc + (size_t)(tn * 128 + row) * KD + schunk * 8;
    }

    f32x4 acc[4][4];
    #pragma unroll
    for (int mi = 0; mi < 4; ++mi)
        #pragma unroll
        for (int ni = 0; ni < 4; ++ni)
            acc[mi][ni] = (f32x4){0.f, 0.f, 0.f, 0.f};

    auto stage = [&](int sb, int kofe) {
        #pragma unroll
        for (int i = 0; i < 4; ++i)
            GLOAD16(aptr[i] + kofe, ldsr + sb + (i * 8 + wid) * 1024);
        #pragma unroll
        for (int j = 0; j < 2; ++j)
            GLOAD16(bptr[j] + kofe, ldsr + sb + ABYTES + (j * 8 + wid) * 1024);
    };

    // prologue: stage tiles 0 and 1; wait tile 0 only (tile 1's 6 loads stay in flight)
    stage(0, 0);
    stage(BUFB, 64);
    asm volatile("s_waitcnt vmcnt(6)" ::: "memory");
    __builtin_amdgcn_s_barrier();

    int cb = 0, sb2 = 2 * BUFB;
    int kofe = 128;
    for (int t = 0; t < NT; ++t) {
        // 1) frag ds_reads from current buffer (swizzled -> bank-uniform b128)
        bf16x8 af[8], bfv[8];
        #pragma unroll
        for (int kb = 0; kb < 2; ++kb)
            #pragma unroll
            for (int mi = 0; mi < 4; ++mi) {
                int row = wm + mi * 16 + lr;
                af[kb * 4 + mi] = *(const bf16x8*)(ldsr + cb + row * 128 + (((kb * 4 + lg) ^ (lr & 7)) * 16));
            }
        #pragma unroll
        for (int kb = 0; kb < 2; ++kb)
            #pragma unroll
            for (int ni = 0; ni < 4; ++ni) {
                int row = wn + ni * 16 + lr;
                bfv[kb * 4 + ni] = *(const bf16x8*)(ldsr + cb + ABYTES + row * 128 + (((kb * 4 + lg) ^ (lr & 7)) * 16));
            }
        // 2) issue stage of tile t+2 (completes by end of NEXT phase)
        if (t < NT - 2) { stage(sb2, kofe); kofe += 64; }
        // 3) MFMA cluster
        __builtin_amdgcn_s_setprio(1);
        #pragma unroll
        for (int kb = 0; kb < 2; ++kb)
            #pragma unroll
            for (int mi = 0; mi < 4; ++mi)
                #pragma unroll
                for (int ni = 0; ni < 4; ++ni)
                    acc[mi][ni] = __builtin_amdgcn_mfma_f32_16x16x32_bf16(af[kb * 4 + mi], bfv[kb * 4 + ni], acc[mi][ni], 0, 0, 0);
        __builtin_amdgcn_s_setprio(0);
        // 4) counted wait: drain tile t+1's 6 loads; keep t+2's 6 in flight across the barrier
        if (t < NT - 2)       { asm volatile("s_waitcnt vmcnt(6)" ::: "memory"); }
        else if (t == NT - 2) { asm volatile("s_waitcnt vmcnt(0)" ::: "memory"); }
        if (t < NT - 1) __builtin_amdgcn_s_barrier();
        cb += BUFB;  if (cb == 3 * BUFB)  cb = 0;
        sb2 += BUFB; if (sb2 == 3 * BUFB) sb2 = 0;
    }

    // ---- epilogue ----
    if (IS_G1) {
        const float* be = bias + e * F_;
        const int pad = ((cnt + 127) >> 7) << 7;
        #pragma unroll
        for (int mi = 0; mi < 4; ++mi) {
            #pragma unroll
            for (int j = 0; j < 4; ++j) {
                int rl = tm * 256 + wm + mi * 16 + lg * 4 + j;
                if (rl < pad) {
                    size_t srow = (size_t)(base + rl) * F_;
                    #pragma unroll
                    for (int ni = 0; ni < 4; ++ni) {
                        int f = tn * 128 + wn + ni * 16 + lr;
                        hOut[srow + f] = f2b(gelu_f(acc[mi][ni][j] + be[f]));
                    }
                }
            }
        }
    } else {
        const float* be = bias + e * D_;
        #pragma unroll
        for (int mi = 0; mi < 4; ++mi) {
            #pragma unroll
            for (int j = 0; j < 4; ++j) {
                int rl = tm * 256 + wm + mi * 16 + lg * 4 + j;
                if (rl < cnt) {
                    int tkn = idx_e[rl];
                    float cw = combine[tkn * E_ + e];
                    float* orow = out + (size_t)tkn * D_;
                    #pragma unroll
                    for (int ni = 0; ni < 4; ++ni) {
                        int d = tn * 128 + wn + ni * 16 + lr;
                        atomicAdd(&orow[d], cw * (acc[mi][ni][j] + be[d]));
                    }
                }
            }
        }
    }
}

__global__ void loss_kernel(const int* __restrict__ fcnt, const float* __restrict__ psum,
                            float* __restrict__ dst) {
    if (threadIdx.x == 0 && blockIdx.x == 0) {
        float loss = 0.f;
        for (int e = 0; e < E_; ++e) {
            float fs = 0.f, Ps = 0.f;
            for (int s = 0; s < 64; ++s) { fs += (float)fcnt[s * E_ + e]; Ps += psum[s * E_ + e]; }
            loss += (fs / (float)T_) * (Ps / (float)T_);
        }
        *dst = LBW_ * (float)E_ * loss;
    }
}

__global__ void sentinel_kernel(float* __restrict__ dst) {
    if (threadIdx.x == 0) dst[0] = -12345.0f;
}

extern "C" void kernel_launch(void* const* d_in, const int* in_sizes, int n_in,
                              void* d_out, int out_size, void* d_ws, size_t ws_size,
                              hipStream_t stream)
{
    const float* x  = (const float*)d_in[0];
    const float* ew = (const float*)d_in[1];
    const float* gw = (const float*)d_in[2];
    const float* gb = (const float*)d_in[3];
    const float* w1 = (const float*)d_in[4];
    const float* b1 = (const float*)d_in[5];
    const float* w2 = (const float*)d_in[6];
    const float* b2 = (const float*)d_in[7];
    float* out = (float*)d_out;

    char* ws = (char*)d_ws;
    size_t o = 0;
    u16* w1t = (u16*)(ws + o); o += (size_t)E_ * D_ * F_ * 2;
    u16* w2t = (u16*)(ws + o); o += (size_t)E_ * F_ * D_ * 2;
    u16* xb  = (u16*)(ws + o); o += (size_t)T_ * D_ * 2;
    u16* h   = (u16*)(ws + o); o += (size_t)HROWS_ * F_ * 2;
    float* combine = (float*)(ws + o); o += (size_t)T_ * E_ * 4;
    int* idx = (int*)(ws + o); o += (size_t)E_ * T_ * 4;
    size_t zoff = o;
    int* cnt   = (int*)(ws + o); o += 128;
    int* fcnt  = (int*)(ws + o); o += 64 * E_ * 4;
    float* psum = (float*)(ws + o); o += 64 * E_ * 4;
    int* off   = (int*)(ws + o); o += 128;
    const size_t ws_needed = o;

    if (ws_size < ws_needed) {
        hipMemsetAsync(d_out, 0, (size_t)out_size * sizeof(float), stream);
        sentinel_kernel<<<1, 64, 0, stream>>>(out + (size_t)out_size - 1);
        return;
    }

    hipMemsetAsync(ws + zoff, 0, ws_needed - zoff, stream);
    hipMemsetAsync(d_out, 0, (size_t)out_size * sizeof(float), stream);

    cvt_T_kernel<<<dim3(F_ / 64, D_ / 64, E_), 256, 0, stream>>>(w1, w1t, D_, F_);
    cvt_T_kernel<<<dim3(D_ / 64, F_ / 64, E_), 256, 0, stream>>>(w2, w2t, F_, D_);
    gate_kernel<<<T_, 64, 0, stream>>>(x, ew, gw, gb, xb, combine, idx, cnt, fcnt, psum);
    offsets_kernel<<<1, 64, 0, stream>>>(cnt, off);
    // 1D grid: gid = e + 8*tm + 256*tn  (e->XCD, tm fast within XCD)
    moe_gemm_kernel<16, true><<<256 * (F_ / 128), 512, 0, stream>>>(
        xb, w1t, b1, nullptr, idx, cnt, off, h, nullptr);
    moe_gemm_kernel<64, false><<<256 * (D_ / 128), 512, 0, stream>>>(
        h, w2t, b2, combine, idx, cnt, off, nullptr, out);
    loss_kernel<<<1, 64, 0, stream>>>(fcnt, psum, out + (size_t)out_size - 1);
}

// Round 6
// 896.660 us; speedup vs baseline: 1.2753x; 1.2753x over previous
//
#include <hip/hip_runtime.h>
#include <math.h>

#define B_ 4
#define S_ 2048
#define D_ 1024
#define F_ 4096
#define E_ 8
#define T_ 8192
#define LBW_ 0.01f
#define HROWS_ 17408   // sum of per-expert 128-padded counts <= 16384 + 8*127
#define NTILE_MAX 72   // max total 256-row M-tiles across experts

typedef unsigned short u16;
typedef __attribute__((ext_vector_type(8))) short bf16x8;
typedef __attribute__((ext_vector_type(4))) float f32x4;

#define GLOAD16(gp, lp) __builtin_amdgcn_global_load_lds( \
    (const __attribute__((address_space(1))) void*)(gp),  \
    (__attribute__((address_space(3))) void*)(lp), 16, 0, 0)

#define MEMBAR() asm volatile("" ::: "memory")
#define BARRIER() do { MEMBAR(); __builtin_amdgcn_s_barrier(); MEMBAR(); } while (0)

__device__ __forceinline__ u16 f2b(float f) {
    unsigned u = __float_as_uint(f);
    u = (u + 0x7FFFu + ((u >> 16) & 1u)) >> 16;   // RNE f32 -> bf16
    return (u16)u;
}
__device__ __forceinline__ float gelu_f(float v) {
    return 0.5f * v * (1.0f + erff(v * 0.70710678118654752440f));
}

// ------- per-expert transpose + convert: src (R x C f32) -> dst (C x R bf16) -------
__global__ __launch_bounds__(256) void cvt_T_kernel(const float* __restrict__ src,
                                                    u16* __restrict__ dst, int R, int C) {
    __shared__ u16 t[64][72];
    const int e = blockIdx.z;
    const float* s = src + (size_t)e * R * C;
    u16* d = dst + (size_t)e * R * C;
    const int r0 = blockIdx.y * 64, c0 = blockIdx.x * 64;
    const int tid = threadIdx.x;
    {
        int rr = tid >> 2, cq = (tid & 3) * 16;
        #pragma unroll
        for (int j = 0; j < 16; j += 4) {
            float4 v = *(const float4*)(s + (size_t)(r0 + rr) * C + c0 + cq + j);
            t[cq + j + 0][rr] = f2b(v.x);
            t[cq + j + 1][rr] = f2b(v.y);
            t[cq + j + 2][rr] = f2b(v.z);
            t[cq + j + 3][rr] = f2b(v.w);
        }
    }
    __syncthreads();
    {
        int cr = tid >> 2, rq = (tid & 3) * 16;
        #pragma unroll
        for (int j = 0; j < 16; j += 8) {
            int4 pk; u16* pw = (u16*)&pk;
            #pragma unroll
            for (int jj = 0; jj < 8; ++jj) pw[jj] = t[cr][rq + j + jj];
            *(int4*)(d + (size_t)(c0 + cr) * R + r0 + rq + j) = pk;
        }
    }
}

// ------- gate: f64 logits, softmax, top-2, routing lists, loss partials; also x->bf16 -------
__global__ __launch_bounds__(64) void gate_kernel(
    const float* __restrict__ x, const float* __restrict__ ew,
    const float* __restrict__ gw, const float* __restrict__ gb,
    u16* __restrict__ xb,
    float* __restrict__ combine, int* __restrict__ idx, int* __restrict__ cnt,
    int* __restrict__ fcnt, float* __restrict__ psum)
{
    const int t = blockIdx.x, l = threadIdx.x;
    const float* xr = x + (size_t)t * D_;
    double acc[E_];
    #pragma unroll
    for (int e = 0; e < E_; ++e) acc[e] = 0.0;
    u16 xw[16];
    #pragma unroll
    for (int kk = 0; kk < 16; kk += 4) {
        float4 xv = *(const float4*)(xr + l * 16 + kk);
        float xs[4] = {xv.x, xv.y, xv.z, xv.w};
        #pragma unroll
        for (int j = 0; j < 4; ++j) {
            xw[kk + j] = f2b(xs[j]);
            const float* gr = gw + (size_t)(l * 16 + kk + j) * E_;
            float4 g0 = *(const float4*)(gr);
            float4 g1 = *(const float4*)(gr + 4);
            acc[0] += (double)xs[j] * g0.x;  acc[1] += (double)xs[j] * g0.y;
            acc[2] += (double)xs[j] * g0.z;  acc[3] += (double)xs[j] * g0.w;
            acc[4] += (double)xs[j] * g1.x;  acc[5] += (double)xs[j] * g1.y;
            acc[6] += (double)xs[j] * g1.z;  acc[7] += (double)xs[j] * g1.w;
        }
    }
    *(int4*)(xb + (size_t)t * D_ + l * 16)     = *(int4*)(xw);
    *(int4*)(xb + (size_t)t * D_ + l * 16 + 8) = *(int4*)(xw + 8);
    #pragma unroll
    for (int e = 0; e < E_; ++e) {
        #pragma unroll
        for (int m = 32; m > 0; m >>= 1) acc[e] += __shfl_xor(acc[e], m);
    }
    if (l == 0) {
        const int b = t / S_;
        double p[E_]; double mx = -1e300;
        #pragma unroll
        for (int e = 0; e < E_; ++e) {
            p[e] = acc[e] + (double)gb[e] + (double)ew[b * E_ + e];
            mx = fmax(mx, p[e]);
        }
        double s = 0.0;
        #pragma unroll
        for (int e = 0; e < E_; ++e) { p[e] = exp(p[e] - mx); s += p[e]; }
        double inv = 1.0 / s;
        #pragma unroll
        for (int e = 0; e < E_; ++e) p[e] *= inv;
        double m1 = -1.0; int e1 = 0;
        #pragma unroll
        for (int e = 0; e < E_; ++e) if (p[e] > m1) { m1 = p[e]; e1 = e; }
        double m2 = -1.0; int e2 = 0;
        #pragma unroll
        for (int e = 0; e < E_; ++e) if (e != e1 && p[e] > m2) { m2 = p[e]; e2 = e; }
        float c1 = (float)(m1 / (m1 + m2)), c2 = (float)(m2 / (m1 + m2));
        #pragma unroll
        for (int e = 0; e < E_; ++e)
            combine[t * E_ + e] = (e == e1) ? c1 : ((e == e2) ? c2 : 0.0f);
        int q1 = atomicAdd(&cnt[e1], 1); idx[e1 * T_ + q1] = t;
        int q2 = atomicAdd(&cnt[e2], 1); idx[e2 * T_ + q2] = t;
        atomicAdd(&fcnt[(t & 63) * E_ + e1], 1);
        #pragma unroll
        for (int e = 0; e < E_; ++e) atomicAdd(&psum[(t & 63) * E_ + e], (float)p[e]);
    }
}

// ------- offsets + balanced M-tile table (decouples tiles from experts) -------
__global__ void tiletab_kernel(const int* __restrict__ cnt, int* __restrict__ off,
                               int* __restrict__ table, int* __restrict__ ntab) {
    if (threadIdx.x == 0 && blockIdx.x == 0) {
        int o = 0, k = 0;
        for (int e = 0; e < E_; ++e) {
            off[e] = o;
            int pad = ((cnt[e] + 127) >> 7) << 7;
            o += pad;
            int nt = (pad + 255) >> 8;
            for (int i = 0; i < nt; ++i) table[k++] = e | (i << 4);
        }
        *ntab = k;
    }
}

// ---- 8-phase 256x256xBK64 grouped GEMM, dbuf 128KB, counted vmcnt(6), never drains ----
// Chunk order per K-tile: [A0(rows0-63) A1(128-191) | B0 B1 | B2 B3 | A2(64-127) A3(192-255)]
// issued at phases [3(prev-prev) | 0(prev) | 1(prev) | 2(prev)]; per-phase vmcnt(6) => each
// phase's reads were confirmed by the previous phase's wait+barrier (full FIFO ledger verified).
template<int NT, int NTN, bool IS_G1>
__global__ __launch_bounds__(512, 2) void moe_gemm8(
    const u16* __restrict__ Aglob, const u16* __restrict__ Wt,
    const float* __restrict__ bias, const float* __restrict__ combine,
    const int* __restrict__ idxAll, const int* __restrict__ cntAll,
    const int* __restrict__ off, const int* __restrict__ table,
    const int* __restrict__ ntab,
    u16* __restrict__ hOut, float* __restrict__ out)
{
    constexpr int KD = NT * 64;
    constexpr int NWG = NTILE_MAX * NTN;
    const int gid2 = ((int)blockIdx.x & 7) * (NWG >> 3) + ((int)blockIdx.x >> 3);
    const int tn = gid2 / NTILE_MAX;          // same tn across an XCD chunk -> B-strip L2-resident
    const int ti = gid2 % NTILE_MAX;
    if (ti >= *ntab) return;
    const int ent = table[ti];
    const int e = ent & 15, tm = ent >> 4;
    const int cnt = cntAll[e], base = off[e];
    const int* idx_e = idxAll + e * T_;
    const u16* Bsrc = Wt + (size_t)e * ((size_t)D_ * F_);

    __shared__ __align__(16) char lds[131072];   // 2 bufs x (A 32KB + B 32KB)

    const int tid = threadIdx.x;
    const int l = tid & 63, wid = tid >> 6;
    const int h = wid >> 2, g = wid & 3;         // m-half (0/1), n-group (0..3)
    const int lr = l & 15, lg = l >> 4;

    // ---- stage source pointers (both-sides XOR chunk swizzle, verified conflict-free) ----
    const int rl = wid * 8 + (l >> 3);           // row within 64-row chunk
    const int sk8 = (((l & 7) ^ ((l >> 3) & 7)) << 3);
    const u16* aP[4]; const u16* bP[4];
    {
        const int crow[4] = { rl, 128 + rl, 64 + rl, 192 + rl };
        #pragma unroll
        for (int c = 0; c < 4; ++c) {
            int r = tm * 256 + crow[c];
            if (IS_G1) {
                int tok = (r < cnt) ? idx_e[r] : idx_e[0];
                aP[c] = Aglob + (size_t)tok * KD + sk8;
            } else {
                int hr = base + r; if (hr > HROWS_ - 1) hr = HROWS_ - 1;
                aP[c] = Aglob + (size_t)hr * KD + sk8;
            }
        }
        const int g2 = rl >> 5, o5 = rl & 31;
        const int ccol[4] = { g2 * 64 + o5,      (2 + g2) * 64 + o5,
                              g2 * 64 + 32 + o5, (2 + g2) * 64 + 32 + o5 };
        #pragma unroll
        for (int c = 0; c < 4; ++c)
            bP[c] = Bsrc + (size_t)(tn * 256 + ccol[c]) * KD + sk8;
    }
    const int sdst = wid * 1024;

    f32x4 acc[8][4];
    #pragma unroll
    for (int mi = 0; mi < 8; ++mi)
        #pragma unroll
        for (int ni = 0; ni < 4; ++ni) acc[mi][ni] = (f32x4){0.f,0.f,0.f,0.f};

    auto stageA = [&](int c, int buf, int kof) {
        GLOAD16(aP[c] + kof, lds + buf * 65536 + c * 8192 + sdst);
    };
    auto stageB = [&](int c, int buf, int kof) {
        GLOAD16(bP[c] + kof, lds + buf * 65536 + 32768 + c * 8192 + sdst);
    };

    // prologue: tile0 in FIFO order, then tile1's A0A1; confirm tile0 front, enter loop
    stageA(0,0,0); stageA(1,0,0);
    stageB(0,0,0); stageB(1,0,0); stageB(2,0,0); stageB(3,0,0);
    stageA(2,0,0); stageA(3,0,0);
    stageA(0,1,64); stageA(1,1,64);
    asm volatile("s_waitcnt vmcnt(6)" ::: "memory");
    BARRIER();

    const int koff0 = ((lg ^ (lr & 7)) << 4);
    bf16x8 a[8], blo[4], bhi[4];

    for (int t = 0; t < NT; ++t) {
        const int cb = (t & 1) * 65536;
        const int nbuf = (t + 1) & 1;
        const int kof1 = (t + 1) * 64, kof2 = (t + 2) * 64;
        // ================ phase 0: read A-low + B-low, issue B0B1(t+1), MFMA Q0 ================
        #pragma unroll
        for (int kb = 0; kb < 2; ++kb) {
            const int ko = koff0 ^ (kb << 6);
            #pragma unroll
            for (int mi = 0; mi < 4; ++mi)
                a[kb*4+mi] = *(const bf16x8*)(lds + cb + (h*64 + mi*16 + lr)*128 + ko);
            #pragma unroll
            for (int ni = 0; ni < 2; ++ni)
                blo[kb*2+ni] = *(const bf16x8*)(lds + cb + 32768 + (g*32 + ni*16 + lr)*128 + ko);
        }
        if (t + 1 < NT) { stageB(0, nbuf, kof1); stageB(1, nbuf, kof1); }
        if (t == NT - 1) asm volatile("s_waitcnt vmcnt(2)" ::: "memory");
        else             asm volatile("s_waitcnt vmcnt(6)" ::: "memory");
        BARRIER();
        __builtin_amdgcn_s_setprio(1);
        #pragma unroll
        for (int kb = 0; kb < 2; ++kb)
            #pragma unroll
            for (int mi = 0; mi < 4; ++mi)
                #pragma unroll
                for (int ni = 0; ni < 2; ++ni)
                    acc[mi][ni] = __builtin_amdgcn_mfma_f32_16x16x32_bf16(a[kb*4+mi], blo[kb*2+ni], acc[mi][ni], 0,0,0);
        __builtin_amdgcn_s_setprio(0);
        BARRIER();
        // ================ phase 1: read B-high, issue B2B3(t+1), MFMA Q1 ================
        #pragma unroll
        for (int kb = 0; kb < 2; ++kb) {
            const int ko = koff0 ^ (kb << 6);
            #pragma unroll
            for (int ni = 0; ni < 2; ++ni)
                bhi[kb*2+ni] = *(const bf16x8*)(lds + cb + 32768 + (128 + g*32 + ni*16 + lr)*128 + ko);
        }
        if (t + 1 < NT) { stageB(2, nbuf, kof1); stageB(3, nbuf, kof1); }
        if (t == NT - 1) asm volatile("s_waitcnt vmcnt(0)" ::: "memory");
        else             asm volatile("s_waitcnt vmcnt(6)" ::: "memory");
        BARRIER();
        __builtin_amdgcn_s_setprio(1);
        #pragma unroll
        for (int kb = 0; kb < 2; ++kb)
            #pragma unroll
            for (int mi = 0; mi < 4; ++mi)
                #pragma unroll
                for (int ni = 0; ni < 2; ++ni)
                    acc[mi][2+ni] = __builtin_amdgcn_mfma_f32_16x16x32_bf16(a[kb*4+mi], bhi[kb*2+ni], acc[mi][2+ni], 0,0,0);
        __builtin_amdgcn_s_setprio(0);
        BARRIER();
        // ================ phase 2: read A-high, issue A2A3(t+1), MFMA Q2 ================
        #pragma unroll
        for (int kb = 0; kb < 2; ++kb) {
            const int ko = koff0 ^ (kb << 6);
            #pragma unroll
            for (int mi = 0; mi < 4; ++mi)
                a[kb*4+mi] = *(const bf16x8*)(lds + cb + (128 + h*64 + mi*16 + lr)*128 + ko);
        }
        if (t + 1 < NT) { stageA(2, nbuf, kof1); stageA(3, nbuf, kof1); }
        if (t < NT - 1)  asm volatile("s_waitcnt vmcnt(6)" ::: "memory");
        BARRIER();
        __builtin_amdgcn_s_setprio(1);
        #pragma unroll
        for (int kb = 0; kb < 2; ++kb)
            #pragma unroll
            for (int mi = 0; mi < 4; ++mi)
                #pragma unroll
                for (int ni = 0; ni < 2; ++ni)
                    acc[4+mi][ni] = __builtin_amdgcn_mfma_f32_16x16x32_bf16(a[kb*4+mi], blo[kb*2+ni], acc[4+mi][ni], 0,0,0);
        __builtin_amdgcn_s_setprio(0);
        BARRIER();
        // ================ phase 3: issue A0A1(t+2) into current buf, MFMA Q3 ================
        if (t + 2 < NT)      { stageA(0, t & 1, kof2); stageA(1, t & 1, kof2); }
        if (t == NT - 2)      asm volatile("s_waitcnt vmcnt(4)" ::: "memory");
        else if (t < NT - 2)  asm volatile("s_waitcnt vmcnt(6)" ::: "memory");
        BARRIER();
        __builtin_amdgcn_s_setprio(1);
        #pragma unroll
        for (int kb = 0; kb < 2; ++kb)
            #pragma unroll
            for (int mi = 0; mi < 4; ++mi)
                #pragma unroll
                for (int ni = 0; ni < 2; ++ni)
                    acc[4+mi][2+ni] = __builtin_amdgcn_mfma_f32_16x16x32_bf16(a[kb*4+mi], bhi[kb*2+ni], acc[4+mi][2+ni], 0,0,0);
        __builtin_amdgcn_s_setprio(0);
        BARRIER();
    }

    // ---- epilogue: C/D frag row = lg*4+j, col = lr; wave tile 128x64 at (h*128, g*64) ----
    const int wm = h * 128, wn = g * 64;
    if (IS_G1) {
        const float* be = bias + e * F_;
        const int pad = ((cnt + 127) >> 7) << 7;
        #pragma unroll
        for (int mi = 0; mi < 8; ++mi) {
            #pragma unroll
            for (int j = 0; j < 4; ++j) {
                int rl2 = tm * 256 + wm + mi * 16 + lg * 4 + j;
                if (rl2 < pad) {
                    size_t srow = (size_t)(base + rl2) * F_;
                    #pragma unroll
                    for (int ni = 0; ni < 4; ++ni) {
                        int f = tn * 256 + wn + ni * 16 + lr;
                        hOut[srow + f] = f2b(gelu_f(acc[mi][ni][j] + be[f]));
                    }
                }
            }
        }
    } else {
        const float* be = bias + e * D_;
        #pragma unroll
        for (int mi = 0; mi < 8; ++mi) {
            #pragma unroll
            for (int j = 0; j < 4; ++j) {
                int rl2 = tm * 256 + wm + mi * 16 + lg * 4 + j;
                if (rl2 < cnt) {
                    int tkn = idx_e[rl2];
                    float cw = combine[tkn * E_ + e];
                    float* orow = out + (size_t)tkn * D_;
                    #pragma unroll
                    for (int ni = 0; ni < 4; ++ni) {
                        int d = tn * 256 + wn + ni * 16 + lr;
                        atomicAdd(&orow[d], cw * (acc[mi][ni][j] + be[d]));
                    }
                }
            }
        }
    }
}

__global__ void loss_kernel(const int* __restrict__ fcnt, const float* __restrict__ psum,
                            float* __restrict__ dst) {
    if (threadIdx.x == 0 && blockIdx.x == 0) {
        float loss = 0.f;
        for (int e = 0; e < E_; ++e) {
            float fs = 0.f, Ps = 0.f;
            for (int s = 0; s < 64; ++s) { fs += (float)fcnt[s * E_ + e]; Ps += psum[s * E_ + e]; }
            loss += (fs / (float)T_) * (Ps / (float)T_);
        }
        *dst = LBW_ * (float)E_ * loss;
    }
}

__global__ void sentinel_kernel(float* __restrict__ dst) {
    if (threadIdx.x == 0) dst[0] = -12345.0f;
}

extern "C" void kernel_launch(void* const* d_in, const int* in_sizes, int n_in,
                              void* d_out, int out_size, void* d_ws, size_t ws_size,
                              hipStream_t stream)
{
    const float* x  = (const float*)d_in[0];
    const float* ew = (const float*)d_in[1];
    const float* gw = (const float*)d_in[2];
    const float* gb = (const float*)d_in[3];
    const float* w1 = (const float*)d_in[4];
    const float* b1 = (const float*)d_in[5];
    const float* w2 = (const float*)d_in[6];
    const float* b2 = (const float*)d_in[7];
    float* out = (float*)d_out;

    char* ws = (char*)d_ws;
    size_t o = 0;
    u16* w1t = (u16*)(ws + o); o += (size_t)E_ * D_ * F_ * 2;
    u16* w2t = (u16*)(ws + o); o += (size_t)E_ * F_ * D_ * 2;
    u16* xb  = (u16*)(ws + o); o += (size_t)T_ * D_ * 2;
    u16* h   = (u16*)(ws + o); o += (size_t)HROWS_ * F_ * 2;
    float* combine = (float*)(ws + o); o += (size_t)T_ * E_ * 4;
    int* idx = (int*)(ws + o); o += (size_t)E_ * T_ * 4;
    size_t zoff = o;
    int* cnt   = (int*)(ws + o); o += 128;
    int* fcnt  = (int*)(ws + o); o += 64 * E_ * 4;
    float* psum = (float*)(ws + o); o += 64 * E_ * 4;
    int* off   = (int*)(ws + o); o += 128;
    int* table = (int*)(ws + o); o += 512;
    int* ntab  = (int*)(ws + o); o += 128;
    const size_t ws_needed = o;

    if (ws_size < ws_needed) {
        hipMemsetAsync(d_out, 0, (size_t)out_size * sizeof(float), stream);
        sentinel_kernel<<<1, 64, 0, stream>>>(out + (size_t)out_size - 1);
        return;
    }

    hipMemsetAsync(ws + zoff, 0, ws_needed - zoff, stream);
    hipMemsetAsync(d_out, 0, (size_t)out_size * sizeof(float), stream);

    cvt_T_kernel<<<dim3(F_ / 64, D_ / 64, E_), 256, 0, stream>>>(w1, w1t, D_, F_);
    cvt_T_kernel<<<dim3(D_ / 64, F_ / 64, E_), 256, 0, stream>>>(w2, w2t, F_, D_);
    gate_kernel<<<T_, 64, 0, stream>>>(x, ew, gw, gb, xb, combine, idx, cnt, fcnt, psum);
    tiletab_kernel<<<1, 64, 0, stream>>>(cnt, off, table, ntab);
    moe_gemm8<16, 16, true><<<NTILE_MAX * 16, 512, 0, stream>>>(
        xb, w1t, b1, nullptr, idx, cnt, off, table, ntab, h, nullptr);
    moe_gemm8<64, 4, false><<<NTILE_MAX * 4, 512, 0, stream>>>(
        h, w2t, b2, combine, idx, cnt, off, table, ntab, nullptr, out);
    loss_kernel<<<1, 64, 0, stream>>>(fcnt, psum, out + (size_t)out_size - 1);
}